// Round 8
// baseline (276.030 us; speedup 1.0000x reference)
//
#include <hip/hip_runtime.h>
#include <math.h>

#define NSH 1195
#define NU  805
#define NI  390
#define DD  64
#define BROWS 65536
#define ESH 100000
#define KPAD 416   // 13*32
#define NUPAD 832  // 13*64, eh16 padded rows

typedef _Float16 f16;
typedef _Float16 f16x2 __attribute__((ext_vector_type(2)));
typedef _Float16 f16x8 __attribute__((ext_vector_type(8)));
typedef float f32x4 __attribute__((ext_vector_type(4)));

// ---------------- ws layout (float units) ----------------
#define OFF_STATS  0u        // 128
#define OFF_ESWT   128u      // 64*416 f16 = 13312 floats
#define OFF_EH     13440u    // 832*64 f16 = 26624 floats
#define OFF_HIST   40064u    // 1280 ints
#define ZERO_FLOATS 41344u
#define OFF_ROWPTR 41344u    // 1280 ints
#define OFF_CURSOR 42624u    // 1280 ints
#define OFF_COLIDX 43904u    // 100096 ints
#define OFF_H1     144000u   // 76480
#define OFF_EPRE   220480u   // 4194304

// ---------------- CSR build ----------------
__global__ __launch_bounds__(256) void hist_kernel(const int* __restrict__ edges,
                                                   int* __restrict__ hist) {
    int e = blockIdx.x * 256 + threadIdx.x;
    if (e < ESH) atomicAdd(&hist[edges[ESH + e]], 1);
}

__global__ __launch_bounds__(1024) void scan_kernel(const int* __restrict__ hist,
                                                    int* __restrict__ row_ptr,
                                                    int* __restrict__ cursor) {
    __shared__ int s[2048];
    int t = threadIdx.x;
    s[t] = (t < NSH) ? hist[t] : 0;
    s[t + 1024] = (t + 1024 < NSH) ? hist[t + 1024] : 0;
    __syncthreads();
    for (int off = 1; off < 2048; off <<= 1) {
        int a = s[t], b = s[t + 1024];
        int aa = (t >= off) ? s[t - off] : 0;
        int bb = s[t + 1024 - off];
        __syncthreads();
        s[t] = a + aa;
        s[t + 1024] = b + bb;
        __syncthreads();
    }
    if (t == 0) row_ptr[0] = 0;
    for (int i = t; i < NSH; i += 1024) {
        row_ptr[i + 1] = s[i];
        cursor[i] = (i == 0) ? 0 : s[i - 1];
    }
}

__global__ __launch_bounds__(256) void scatter_kernel(const int* __restrict__ edges,
                                                      int* __restrict__ cursor,
                                                      int* __restrict__ col_idx) {
    int e = blockIdx.x * 256 + threadIdx.x;
    if (e < ESH) {
        int t = edges[ESH + e];
        int pos = atomicAdd(&cursor[t], 1);
        col_idx[pos] = edges[e];
    }
}

// ---------------- layer 1: gather + transform ----------------
__global__ __launch_bounds__(256) void gcn_gather1(const int* __restrict__ row_ptr,
                                                   const int* __restrict__ col_idx,
                                                   const float* __restrict__ x,
                                                   const float* __restrict__ W,
                                                   const float* __restrict__ b,
                                                   float* __restrict__ out) {
    __shared__ float s_wt[DD * DD];
    __shared__ float s_p[4 * DD];
    int tid = threadIdx.x;
    int w = tid >> 6, lane = tid & 63;
    for (int i = tid; i < DD * DD; i += 256) {
        int j = i >> 6, k = i & 63;
        s_wt[k * DD + j] = W[i];
    }
    int node = blockIdx.x;
    int beg = row_ptr[node], end = row_ptr[node + 1];
    float acc = 0.f;
    for (int e = beg + w; e < end; e += 4)
        acc += x[col_idx[e] * DD + lane];
    s_p[w * DD + lane] = acc;
    __syncthreads();
    float z = s_p[lane] + s_p[DD + lane] + s_p[2 * DD + lane] + s_p[3 * DD + lane];
    __syncthreads();
    if (w == 0) s_p[lane] = z;
    __syncthreads();
    float cntf = (float)(end - beg);
    float o = cntf * b[lane];
    #pragma unroll 8
    for (int k = 0; k < DD; k++)
        o = fmaf(s_p[k], s_wt[k * DD + lane], o);
    float h = tanhf(o / fmaxf(cntf, 1.f));
    if (w == 0) out[node * DD + lane] = h;
}

// ---------------- layer 2 fused ----------------
__global__ __launch_bounds__(256) void gcn2_fused(const int* __restrict__ row_ptr,
                                                  const int* __restrict__ col_idx,
                                                  const float* __restrict__ h1,
                                                  const float* __restrict__ W2,
                                                  const float* __restrict__ b2,
                                                  const float* __restrict__ Wp1,
                                                  const float* __restrict__ bp1,
                                                  const float* __restrict__ Wp2,
                                                  const float* __restrict__ bp2,
                                                  const float* __restrict__ Wm,
                                                  f16* __restrict__ eh16,
                                                  f16* __restrict__ esWT) {
    __shared__ float s_w2[DD * DD], s_p1[DD * DD], s_p2[DD * DD], s_wm[DD * DD];
    __shared__ float s_v[4 * DD];
    int tid = threadIdx.x;
    int w = tid >> 6, lane = tid & 63;
    for (int i = tid; i < DD * DD; i += 256) {
        int j = i >> 6, k = i & 63;
        s_w2[k * DD + j] = W2[i];
        s_p1[k * DD + j] = Wp1[i];
        s_p2[k * DD + j] = Wp2[i];
        s_wm[k * DD + j] = Wm[i];
    }
    int node = blockIdx.x;
    int beg = row_ptr[node], end = row_ptr[node + 1];
    float acc = 0.f;
    for (int e = beg + w; e < end; e += 4)
        acc += h1[col_idx[e] * DD + lane];
    s_v[w * DD + lane] = acc;
    __syncthreads();
    float z = s_v[lane] + s_v[DD + lane] + s_v[2 * DD + lane] + s_v[3 * DD + lane];
    __syncthreads();
    if (w == 0) s_v[lane] = z;
    __syncthreads();
    float cntf = (float)(end - beg);
    float o = cntf * b2[lane];
    #pragma unroll 8
    for (int k = 0; k < DD; k++)
        o = fmaf(s_v[k], s_w2[k * DD + lane], o);
    float h2v = tanhf(o / fmaxf(cntf, 1.f));
    __syncthreads();
    if (w == 0) s_v[lane] = h2v;
    __syncthreads();
    float t = bp1[lane];
    #pragma unroll 8
    for (int k = 0; k < DD; k++)
        t = fmaf(s_v[k], s_p1[k * DD + lane], t);
    t = t > 0.f ? t : expm1f(t);
    __syncthreads();
    if (w == 0) s_v[lane] = t;
    __syncthreads();
    float o2 = bp2[lane];
    #pragma unroll 8
    for (int k = 0; k < DD; k++)
        o2 = fmaf(s_v[k], s_p2[k * DD + lane], o2);
    float sq = o2 * o2;
    #pragma unroll
    for (int off = 1; off < 64; off <<= 1) sq += __shfl_xor(sq, off);
    float r = o2 / sqrtf(sq);
    if (node < NU) {
        if (w == 0) eh16[node * DD + lane] = (f16)r;
    } else {
        __syncthreads();
        if (w == 0) s_v[lane] = r;
        __syncthreads();
        float m = 0.f;
        #pragma unroll 8
        for (int k = 0; k < DD; k++)
            m = fmaf(s_v[k], s_wm[k * DD + lane], m);
        if (w == 0) esWT[lane * KPAD + (node - NU)] = (f16)m;
    }
}

// ---------------- synd_v2: LDS-staged P (f16), rowsum via ones-MFMA ----------------
__global__ __launch_bounds__(256) void synd_v2(const float* __restrict__ P,
                                               const f16* __restrict__ esWT,
                                               const float* __restrict__ bm,
                                               float* __restrict__ e_pre,
                                               float* __restrict__ stats) {
    __shared__ __align__(16) f16 s_P[64 * KPAD];   // 53248 B
    __shared__ float s_stats[128];
    int tid = threadIdx.x;
    if (tid < 128) s_stats[tid] = 0.f;

    for (int i = tid; i < 64 * 13; i += 256) {
        int row = i / 13, j = i - row * 13;
        *(uint32_t*)&s_P[row * KPAD + 390 + j * 2] = 0u;
    }
    const float* Pb = P + (size_t)blockIdx.x * 64 * NI;
    for (int it = 0; it < 25; it++) {
        int f = it * 1024 + tid * 4;
        if (f < 64 * NI) {
            f32x4 v = *(const f32x4*)(Pb + f);
            int row = f / NI;
            int col = f - row * NI;
            *(f16x2*)&s_P[row * KPAD + col] = (f16x2){(f16)v.x, (f16)v.y};
            int row2 = row, col2 = col + 2;
            if (col2 == NI) { row2 = row + 1; col2 = 0; }
            *(f16x2*)&s_P[row2 * KPAD + col2] = (f16x2){(f16)v.z, (f16)v.w};
        }
    }
    __syncthreads();

    int lane = tid & 63, w = tid >> 6;
    int l15 = lane & 15, lk = lane >> 4;
    int rowbase = blockIdx.x * 64 + w * 16;

    f32x4 acc[5];
    #pragma unroll
    for (int ni = 0; ni < 5; ni++) acc[ni] = (f32x4){0.f, 0.f, 0.f, 0.f};

    f16x8 ones;
    #pragma unroll
    for (int i = 0; i < 8; i++) ones[i] = (f16)1.0f;

    const f16* arow = &s_P[(w * 16 + l15) * KPAD];
    const f16* bp[4];
    #pragma unroll
    for (int ni = 0; ni < 4; ni++)
        bp[ni] = esWT + (size_t)(ni * 16 + l15) * KPAD;

    for (int step = 0; step < 13; step++) {
        int kb = step * 32 + lk * 8;
        f16x8 a = *(const f16x8*)(arow + kb);
        f16x8 bfr[4];
        #pragma unroll
        for (int ni = 0; ni < 4; ni++)
            bfr[ni] = *(const f16x8*)(bp[ni] + kb);
        #pragma unroll
        for (int ni = 0; ni < 4; ni++)
            acc[ni] = __builtin_amdgcn_mfma_f32_16x16x32_f16(a, bfr[ni], acc[ni], 0, 0, 0);
        acc[4] = __builtin_amdgcn_mfma_f32_16x16x32_f16(a, ones, acc[4], 0, 0, 0);
    }

    float bmv[4];
    #pragma unroll
    for (int ni = 0; ni < 4; ni++) bmv[ni] = bm[ni * 16 + l15];

    #pragma unroll
    for (int ni = 0; ni < 4; ni++) {
        float s = 0.f, q = 0.f;
        #pragma unroll
        for (int j = 0; j < 4; j++) {
            float v = acc[ni][j] / acc[4][j] + bmv[ni];
            int row = rowbase + lk * 4 + j;
            e_pre[(size_t)row * DD + ni * 16 + l15] = v;
            s += v;
            q = fmaf(v, v, q);
        }
        s += __shfl_xor(s, 16); s += __shfl_xor(s, 32);
        q += __shfl_xor(q, 16); q += __shfl_xor(q, 32);
        if (lk == 0) {
            atomicAdd(&s_stats[ni * 16 + l15], s);
            atomicAdd(&s_stats[64 + ni * 16 + l15], q);
        }
    }
    __syncthreads();
    if (tid < 128) atomicAdd(&stats[tid], s_stats[tid]);
}

// ---------------- out: 4 col-groups (4/3/3/3 tiles), LDS 33KB ----------------
__global__ __launch_bounds__(256) void out_fused(const float* __restrict__ e_pre,
                                                 const f16* __restrict__ eh16,
                                                 const float* __restrict__ stats,
                                                 const float* __restrict__ gamma,
                                                 const float* __restrict__ beta,
                                                 float* __restrict__ out) {
    __shared__ __align__(16) f16 s_eh[256 * DD];
    __shared__ float s_bn[128];
    int tid = threadIdx.x;
    int cg = blockIdx.x;
    int t0 = (cg == 0) ? 0 : cg * 3 + 1;
    int nt = (cg == 0) ? 4 : 3;
    int cbase = t0 * 64;
    int nrows = nt * 64;

    if (tid < 64) {
        float mu  = stats[tid] * (1.0f / 65536.0f);
        float ex2 = stats[64 + tid] * (1.0f / 65536.0f);
        float var = ex2 - mu * mu;
        float rstd = 1.0f / sqrtf(var + 1e-5f);
        float sc = rstd * gamma[tid];
        s_bn[tid] = sc;
        s_bn[64 + tid] = beta[tid] - mu * sc;
    }

    const uint4* src = (const uint4*)(eh16 + (size_t)cbase * DD);
    int nchunks = nrows * 8;
    for (int c = tid; c < nchunks; c += 256) {
        int row = c >> 3, slot = c & 7;
        uint4 v = src[c];
        *(uint4*)&s_eh[row * DD + ((slot ^ (row & 7)) << 3)] = v;
    }
    __syncthreads();

    int lane = tid & 63, w = tid >> 6;
    int l15 = lane & 15, lk = lane >> 4;
    int r0 = blockIdx.y * 64 + w * 16;

    f16x8 afr[2];
    {
        const float* pr = e_pre + (size_t)(r0 + l15) * DD;
        #pragma unroll
        for (int ks = 0; ks < 2; ks++) {
            int kb = ks * 32 + lk * 8;
            f32x4 v0 = *(const f32x4*)&pr[kb];
            f32x4 v1 = *(const f32x4*)&pr[kb + 4];
            f16x8 a;
            #pragma unroll
            for (int i = 0; i < 4; i++) {
                a[i]     = (f16)fmaxf(fmaf(v0[i], s_bn[kb + i],     s_bn[64 + kb + i]),     0.f);
                a[4 + i] = (f16)fmaxf(fmaf(v1[i], s_bn[kb + 4 + i], s_bn[64 + kb + 4 + i]), 0.f);
            }
            afr[ks] = a;
        }
    }

    for (int tt = 0; tt < nt; tt++) {
        f32x4 acc[4];
        #pragma unroll
        for (int c16 = 0; c16 < 4; c16++) acc[c16] = (f32x4){0.f, 0.f, 0.f, 0.f};
        #pragma unroll
        for (int c16 = 0; c16 < 4; c16++) {
            int lc = tt * 64 + c16 * 16 + l15;
            #pragma unroll
            for (int ks = 0; ks < 2; ks++) {
                int slot = (ks * 4 + lk) ^ (lc & 7);
                f16x8 b = *(const f16x8*)&s_eh[lc * DD + (slot << 3)];
                acc[c16] = __builtin_amdgcn_mfma_f32_16x16x32_f16(afr[ks], b, acc[c16], 0, 0, 0);
            }
        }
        #pragma unroll
        for (int c16 = 0; c16 < 4; c16++) {
            int col = cbase + tt * 64 + c16 * 16 + l15;
            if (col < NU) {
                #pragma unroll
                for (int j = 0; j < 4; j++) {
                    int row = r0 + lk * 4 + j;
                    out[(size_t)row * NU + col] = acc[c16][j];
                }
            }
        }
    }
}

// ---------------- launcher (R6 baseline + duplicated out_fused for timing split) ----------------
extern "C" void kernel_launch(void* const* d_in, const int* in_sizes, int n_in,
                              void* d_out, int out_size, void* d_ws, size_t ws_size,
                              hipStream_t stream) {
    const int*   eSH   = (const int*)d_in[0];
    const float* presc = (const float*)d_in[3];
    const float* shemb = (const float*)d_in[4];
    const float* W1  = (const float*)d_in[5];
    const float* b1  = (const float*)d_in[6];
    const float* W2  = (const float*)d_in[7];
    const float* b2  = (const float*)d_in[8];
    const float* Wp1 = (const float*)d_in[9];
    const float* bp1 = (const float*)d_in[10];
    const float* Wp2 = (const float*)d_in[11];
    const float* bp2 = (const float*)d_in[12];
    const float* Wm  = (const float*)d_in[13];
    const float* bm  = (const float*)d_in[14];
    const float* gam = (const float*)d_in[15];
    const float* bet = (const float*)d_in[16];

    float* ws    = (float*)d_ws;
    float* stats = ws + OFF_STATS;
    f16*   esWT  = (f16*)(ws + OFF_ESWT);
    f16*   eh16  = (f16*)(ws + OFF_EH);
    int*   hist  = (int*)(ws + OFF_HIST);
    int*   rowp  = (int*)(ws + OFF_ROWPTR);
    int*   curs  = (int*)(ws + OFF_CURSOR);
    int*   cidx  = (int*)(ws + OFF_COLIDX);
    float* h1    = ws + OFF_H1;
    float* e_pre = ws + OFF_EPRE;
    float* out   = (float*)d_out;

    hipMemsetAsync(ws, 0, ZERO_FLOATS * sizeof(float), stream);

    hist_kernel<<<391, 256, 0, stream>>>(eSH, hist);
    scan_kernel<<<1, 1024, 0, stream>>>(hist, rowp, curs);
    scatter_kernel<<<391, 256, 0, stream>>>(eSH, curs, cidx);
    gcn_gather1<<<NSH, 256, 0, stream>>>(rowp, cidx, shemb, W1, b1, h1);
    gcn2_fused<<<NSH, 256, 0, stream>>>(rowp, cidx, h1, W2, b2,
                                        Wp1, bp1, Wp2, bp2, Wm, eh16, esWT);
    synd_v2<<<1024, 256, 0, stream>>>(presc, esWT, bm, e_pre, stats);
    // measurement: out_fused twice (idempotent). Delta vs R6 == dur(out_fused).
    out_fused<<<dim3(4, 1024), 256, 0, stream>>>(e_pre, eh16, stats, gam, bet, out);
    out_fused<<<dim3(4, 1024), 256, 0, stream>>>(e_pre, eh16, stats, gam, bet, out);
}

// Round 9
// 234.390 us; speedup vs baseline: 1.1777x; 1.1777x over previous
//
#include <hip/hip_runtime.h>
#include <math.h>

#define NSH 1195
#define NU  805
#define NI  390
#define DD  64
#define BROWS 65536
#define ESH 100000
#define KPAD 416   // 13*32
#define NUPAD 832  // 13*64, eh16 padded rows

typedef _Float16 f16;
typedef _Float16 f16x2 __attribute__((ext_vector_type(2)));
typedef _Float16 f16x8 __attribute__((ext_vector_type(8)));
typedef float f32x4 __attribute__((ext_vector_type(4)));

// ---------------- ws layout (float units) ----------------
// stats is now a 64-way spread accumulator: [64 slots][128 channels]
#define OFF_STATS  0u        // 8192 floats
#define OFF_ESWT   8192u     // 64*416 f16 = 13312 floats
#define OFF_EH     21504u    // 832*64 f16 = 26624 floats
#define OFF_HIST   48128u    // 1280 ints
#define ZERO_FLOATS 49408u
#define OFF_ROWPTR 49408u    // 1280 ints
#define OFF_CURSOR 50688u    // 1280 ints
#define OFF_COLIDX 51968u    // 100096 ints
#define OFF_H1     152064u   // 76480
#define OFF_EPRE   228544u   // 4194304

// ---------------- CSR build ----------------
__global__ __launch_bounds__(256) void hist_kernel(const int* __restrict__ edges,
                                                   int* __restrict__ hist) {
    int e = blockIdx.x * 256 + threadIdx.x;
    if (e < ESH) atomicAdd(&hist[edges[ESH + e]], 1);
}

__global__ __launch_bounds__(1024) void scan_kernel(const int* __restrict__ hist,
                                                    int* __restrict__ row_ptr,
                                                    int* __restrict__ cursor) {
    __shared__ int s[2048];
    int t = threadIdx.x;
    s[t] = (t < NSH) ? hist[t] : 0;
    s[t + 1024] = (t + 1024 < NSH) ? hist[t + 1024] : 0;
    __syncthreads();
    for (int off = 1; off < 2048; off <<= 1) {
        int a = s[t], b = s[t + 1024];
        int aa = (t >= off) ? s[t - off] : 0;
        int bb = s[t + 1024 - off];
        __syncthreads();
        s[t] = a + aa;
        s[t + 1024] = b + bb;
        __syncthreads();
    }
    if (t == 0) row_ptr[0] = 0;
    for (int i = t; i < NSH; i += 1024) {
        row_ptr[i + 1] = s[i];
        cursor[i] = (i == 0) ? 0 : s[i - 1];
    }
}

__global__ __launch_bounds__(256) void scatter_kernel(const int* __restrict__ edges,
                                                      int* __restrict__ cursor,
                                                      int* __restrict__ col_idx) {
    int e = blockIdx.x * 256 + threadIdx.x;
    if (e < ESH) {
        int t = edges[ESH + e];
        int pos = atomicAdd(&cursor[t], 1);
        col_idx[pos] = edges[e];
    }
}

// ---------------- layer 1: gather + transform ----------------
__global__ __launch_bounds__(256) void gcn_gather1(const int* __restrict__ row_ptr,
                                                   const int* __restrict__ col_idx,
                                                   const float* __restrict__ x,
                                                   const float* __restrict__ W,
                                                   const float* __restrict__ b,
                                                   float* __restrict__ out) {
    __shared__ float s_wt[DD * DD];
    __shared__ float s_p[4 * DD];
    int tid = threadIdx.x;
    int w = tid >> 6, lane = tid & 63;
    for (int i = tid; i < DD * DD; i += 256) {
        int j = i >> 6, k = i & 63;
        s_wt[k * DD + j] = W[i];
    }
    int node = blockIdx.x;
    int beg = row_ptr[node], end = row_ptr[node + 1];
    float acc = 0.f;
    for (int e = beg + w; e < end; e += 4)
        acc += x[col_idx[e] * DD + lane];
    s_p[w * DD + lane] = acc;
    __syncthreads();
    float z = s_p[lane] + s_p[DD + lane] + s_p[2 * DD + lane] + s_p[3 * DD + lane];
    __syncthreads();
    if (w == 0) s_p[lane] = z;
    __syncthreads();
    float cntf = (float)(end - beg);
    float o = cntf * b[lane];
    #pragma unroll 8
    for (int k = 0; k < DD; k++)
        o = fmaf(s_p[k], s_wt[k * DD + lane], o);
    float h = tanhf(o / fmaxf(cntf, 1.f));
    if (w == 0) out[node * DD + lane] = h;
}

// ---------------- layer 2 fused ----------------
__global__ __launch_bounds__(256) void gcn2_fused(const int* __restrict__ row_ptr,
                                                  const int* __restrict__ col_idx,
                                                  const float* __restrict__ h1,
                                                  const float* __restrict__ W2,
                                                  const float* __restrict__ b2,
                                                  const float* __restrict__ Wp1,
                                                  const float* __restrict__ bp1,
                                                  const float* __restrict__ Wp2,
                                                  const float* __restrict__ bp2,
                                                  const float* __restrict__ Wm,
                                                  f16* __restrict__ eh16,
                                                  f16* __restrict__ esWT) {
    __shared__ float s_w2[DD * DD], s_p1[DD * DD], s_p2[DD * DD], s_wm[DD * DD];
    __shared__ float s_v[4 * DD];
    int tid = threadIdx.x;
    int w = tid >> 6, lane = tid & 63;
    for (int i = tid; i < DD * DD; i += 256) {
        int j = i >> 6, k = i & 63;
        s_w2[k * DD + j] = W2[i];
        s_p1[k * DD + j] = Wp1[i];
        s_p2[k * DD + j] = Wp2[i];
        s_wm[k * DD + j] = Wm[i];
    }
    int node = blockIdx.x;
    int beg = row_ptr[node], end = row_ptr[node + 1];
    float acc = 0.f;
    for (int e = beg + w; e < end; e += 4)
        acc += h1[col_idx[e] * DD + lane];
    s_v[w * DD + lane] = acc;
    __syncthreads();
    float z = s_v[lane] + s_v[DD + lane] + s_v[2 * DD + lane] + s_v[3 * DD + lane];
    __syncthreads();
    if (w == 0) s_v[lane] = z;
    __syncthreads();
    float cntf = (float)(end - beg);
    float o = cntf * b2[lane];
    #pragma unroll 8
    for (int k = 0; k < DD; k++)
        o = fmaf(s_v[k], s_w2[k * DD + lane], o);
    float h2v = tanhf(o / fmaxf(cntf, 1.f));
    __syncthreads();
    if (w == 0) s_v[lane] = h2v;
    __syncthreads();
    float t = bp1[lane];
    #pragma unroll 8
    for (int k = 0; k < DD; k++)
        t = fmaf(s_v[k], s_p1[k * DD + lane], t);
    t = t > 0.f ? t : expm1f(t);
    __syncthreads();
    if (w == 0) s_v[lane] = t;
    __syncthreads();
    float o2 = bp2[lane];
    #pragma unroll 8
    for (int k = 0; k < DD; k++)
        o2 = fmaf(s_v[k], s_p2[k * DD + lane], o2);
    float sq = o2 * o2;
    #pragma unroll
    for (int off = 1; off < 64; off <<= 1) sq += __shfl_xor(sq, off);
    float r = o2 / sqrtf(sq);
    if (node < NU) {
        if (w == 0) eh16[node * DD + lane] = (f16)r;
    } else {
        __syncthreads();
        if (w == 0) s_v[lane] = r;
        __syncthreads();
        float m = 0.f;
        #pragma unroll 8
        for (int k = 0; k < DD; k++)
            m = fmaf(s_v[k], s_wm[k * DD + lane], m);
        if (w == 0) esWT[lane * KPAD + (node - NU)] = (f16)m;
    }
}

// ---------------- synd_v2: LDS-staged P (f16), rowsum via ones-MFMA ----------------
// stats epilogue: 64-way spread atomics -> contention 16/address instead of 1024
__global__ __launch_bounds__(256) void synd_v2(const float* __restrict__ P,
                                               const f16* __restrict__ esWT,
                                               const float* __restrict__ bm,
                                               float* __restrict__ e_pre,
                                               float* __restrict__ stats) {
    __shared__ __align__(16) f16 s_P[64 * KPAD];   // 53248 B
    __shared__ float s_stats[128];
    int tid = threadIdx.x;
    if (tid < 128) s_stats[tid] = 0.f;

    for (int i = tid; i < 64 * 13; i += 256) {
        int row = i / 13, j = i - row * 13;
        *(uint32_t*)&s_P[row * KPAD + 390 + j * 2] = 0u;
    }
    const float* Pb = P + (size_t)blockIdx.x * 64 * NI;
    for (int it = 0; it < 25; it++) {
        int f = it * 1024 + tid * 4;
        if (f < 64 * NI) {
            f32x4 v = *(const f32x4*)(Pb + f);
            int row = f / NI;
            int col = f - row * NI;
            *(f16x2*)&s_P[row * KPAD + col] = (f16x2){(f16)v.x, (f16)v.y};
            int row2 = row, col2 = col + 2;
            if (col2 == NI) { row2 = row + 1; col2 = 0; }
            *(f16x2*)&s_P[row2 * KPAD + col2] = (f16x2){(f16)v.z, (f16)v.w};
        }
    }
    __syncthreads();

    int lane = tid & 63, w = tid >> 6;
    int l15 = lane & 15, lk = lane >> 4;
    int rowbase = blockIdx.x * 64 + w * 16;

    f32x4 acc[5];
    #pragma unroll
    for (int ni = 0; ni < 5; ni++) acc[ni] = (f32x4){0.f, 0.f, 0.f, 0.f};

    f16x8 ones;
    #pragma unroll
    for (int i = 0; i < 8; i++) ones[i] = (f16)1.0f;

    const f16* arow = &s_P[(w * 16 + l15) * KPAD];
    const f16* bp[4];
    #pragma unroll
    for (int ni = 0; ni < 4; ni++)
        bp[ni] = esWT + (size_t)(ni * 16 + l15) * KPAD;

    for (int step = 0; step < 13; step++) {
        int kb = step * 32 + lk * 8;
        f16x8 a = *(const f16x8*)(arow + kb);
        f16x8 bfr[4];
        #pragma unroll
        for (int ni = 0; ni < 4; ni++)
            bfr[ni] = *(const f16x8*)(bp[ni] + kb);
        #pragma unroll
        for (int ni = 0; ni < 4; ni++)
            acc[ni] = __builtin_amdgcn_mfma_f32_16x16x32_f16(a, bfr[ni], acc[ni], 0, 0, 0);
        acc[4] = __builtin_amdgcn_mfma_f32_16x16x32_f16(a, ones, acc[4], 0, 0, 0);
    }

    float bmv[4];
    #pragma unroll
    for (int ni = 0; ni < 4; ni++) bmv[ni] = bm[ni * 16 + l15];

    #pragma unroll
    for (int ni = 0; ni < 4; ni++) {
        float s = 0.f, q = 0.f;
        #pragma unroll
        for (int j = 0; j < 4; j++) {
            float v = acc[ni][j] / acc[4][j] + bmv[ni];
            int row = rowbase + lk * 4 + j;
            e_pre[(size_t)row * DD + ni * 16 + l15] = v;
            s += v;
            q = fmaf(v, v, q);
        }
        s += __shfl_xor(s, 16); s += __shfl_xor(s, 32);
        q += __shfl_xor(q, 16); q += __shfl_xor(q, 32);
        if (lk == 0) {
            atomicAdd(&s_stats[ni * 16 + l15], s);
            atomicAdd(&s_stats[64 + ni * 16 + l15], q);
        }
    }
    __syncthreads();
    // spread: slot = blockIdx & 63; layout stats[slot][128]
    if (tid < 128)
        atomicAdd(&stats[(blockIdx.x & 63) * 128 + tid], s_stats[tid]);
}

// ---------------- out: 4 col-groups (4/3/3/3 tiles), LDS 33KB ----------------
__global__ __launch_bounds__(256) void out_fused(const float* __restrict__ e_pre,
                                                 const f16* __restrict__ eh16,
                                                 const float* __restrict__ stats,
                                                 const float* __restrict__ gamma,
                                                 const float* __restrict__ beta,
                                                 float* __restrict__ out) {
    __shared__ __align__(16) f16 s_eh[256 * DD];
    __shared__ float s_bn[128];
    int tid = threadIdx.x;
    int cg = blockIdx.x;
    int t0 = (cg == 0) ? 0 : cg * 3 + 1;
    int nt = (cg == 0) ? 4 : 3;
    int cbase = t0 * 64;
    int nrows = nt * 64;

    // BN params: reduce the 64-way spread accumulator (coalesced L2 reads)
    if (tid < 64) {
        float s = 0.f, q = 0.f;
        #pragma unroll 8
        for (int k = 0; k < 64; k++) {
            s += stats[k * 128 + tid];
            q += stats[k * 128 + 64 + tid];
        }
        float mu  = s * (1.0f / 65536.0f);
        float ex2 = q * (1.0f / 65536.0f);
        float var = ex2 - mu * mu;
        float rstd = 1.0f / sqrtf(var + 1e-5f);
        float sc = rstd * gamma[tid];
        s_bn[tid] = sc;
        s_bn[64 + tid] = beta[tid] - mu * sc;
    }

    const uint4* src = (const uint4*)(eh16 + (size_t)cbase * DD);
    int nchunks = nrows * 8;
    for (int c = tid; c < nchunks; c += 256) {
        int row = c >> 3, slot = c & 7;
        uint4 v = src[c];
        *(uint4*)&s_eh[row * DD + ((slot ^ (row & 7)) << 3)] = v;
    }
    __syncthreads();

    int lane = tid & 63, w = tid >> 6;
    int l15 = lane & 15, lk = lane >> 4;
    int r0 = blockIdx.y * 64 + w * 16;

    f16x8 afr[2];
    {
        const float* pr = e_pre + (size_t)(r0 + l15) * DD;
        #pragma unroll
        for (int ks = 0; ks < 2; ks++) {
            int kb = ks * 32 + lk * 8;
            f32x4 v0 = *(const f32x4*)&pr[kb];
            f32x4 v1 = *(const f32x4*)&pr[kb + 4];
            f16x8 a;
            #pragma unroll
            for (int i = 0; i < 4; i++) {
                a[i]     = (f16)fmaxf(fmaf(v0[i], s_bn[kb + i],     s_bn[64 + kb + i]),     0.f);
                a[4 + i] = (f16)fmaxf(fmaf(v1[i], s_bn[kb + 4 + i], s_bn[64 + kb + 4 + i]), 0.f);
            }
            afr[ks] = a;
        }
    }

    for (int tt = 0; tt < nt; tt++) {
        f32x4 acc[4];
        #pragma unroll
        for (int c16 = 0; c16 < 4; c16++) acc[c16] = (f32x4){0.f, 0.f, 0.f, 0.f};
        #pragma unroll
        for (int c16 = 0; c16 < 4; c16++) {
            int lc = tt * 64 + c16 * 16 + l15;
            #pragma unroll
            for (int ks = 0; ks < 2; ks++) {
                int slot = (ks * 4 + lk) ^ (lc & 7);
                f16x8 b = *(const f16x8*)&s_eh[lc * DD + (slot << 3)];
                acc[c16] = __builtin_amdgcn_mfma_f32_16x16x32_f16(afr[ks], b, acc[c16], 0, 0, 0);
            }
        }
        #pragma unroll
        for (int c16 = 0; c16 < 4; c16++) {
            int col = cbase + tt * 64 + c16 * 16 + l15;
            if (col < NU) {
                #pragma unroll
                for (int j = 0; j < 4; j++) {
                    int row = r0 + lk * 4 + j;
                    out[(size_t)row * NU + col] = acc[c16][j];
                }
            }
        }
    }
}

// ---------------- launcher ----------------
extern "C" void kernel_launch(void* const* d_in, const int* in_sizes, int n_in,
                              void* d_out, int out_size, void* d_ws, size_t ws_size,
                              hipStream_t stream) {
    const int*   eSH   = (const int*)d_in[0];
    const float* presc = (const float*)d_in[3];
    const float* shemb = (const float*)d_in[4];
    const float* W1  = (const float*)d_in[5];
    const float* b1  = (const float*)d_in[6];
    const float* W2  = (const float*)d_in[7];
    const float* b2  = (const float*)d_in[8];
    const float* Wp1 = (const float*)d_in[9];
    const float* bp1 = (const float*)d_in[10];
    const float* Wp2 = (const float*)d_in[11];
    const float* bp2 = (const float*)d_in[12];
    const float* Wm  = (const float*)d_in[13];
    const float* bm  = (const float*)d_in[14];
    const float* gam = (const float*)d_in[15];
    const float* bet = (const float*)d_in[16];

    float* ws    = (float*)d_ws;
    float* stats = ws + OFF_STATS;
    f16*   esWT  = (f16*)(ws + OFF_ESWT);
    f16*   eh16  = (f16*)(ws + OFF_EH);
    int*   hist  = (int*)(ws + OFF_HIST);
    int*   rowp  = (int*)(ws + OFF_ROWPTR);
    int*   curs  = (int*)(ws + OFF_CURSOR);
    int*   cidx  = (int*)(ws + OFF_COLIDX);
    float* h1    = ws + OFF_H1;
    float* e_pre = ws + OFF_EPRE;
    float* out   = (float*)d_out;

    hipMemsetAsync(ws, 0, ZERO_FLOATS * sizeof(float), stream);

    hist_kernel<<<391, 256, 0, stream>>>(eSH, hist);
    scan_kernel<<<1, 1024, 0, stream>>>(hist, rowp, curs);
    scatter_kernel<<<391, 256, 0, stream>>>(eSH, curs, cidx);
    gcn_gather1<<<NSH, 256, 0, stream>>>(rowp, cidx, shemb, W1, b1, h1);
    gcn2_fused<<<NSH, 256, 0, stream>>>(rowp, cidx, h1, W2, b2,
                                        Wp1, bp1, Wp2, bp2, Wm, eh16, esWT);
    synd_v2<<<1024, 256, 0, stream>>>(presc, esWT, bm, e_pre, stats);
    out_fused<<<dim3(4, 1024), 256, 0, stream>>>(e_pre, eh16, stats, gam, bet, out);
}